// Round 8
// baseline (421.282 us; speedup 1.0000x reference)
//
#include <hip/hip_runtime.h>

#define N_NODES   100000
#define DFEAT     128
#define OUTW      384     // 3 * 128
#define NB        256     // dst buckets
#define NPB       391     // nodes per bucket (256*391 = 100096 >= 100000)
#define BCAP      8192    // per-bucket LDS staging capacity (mean 6250, sigma ~79)
#define BINW      1024    // threads per bin block
#define BINBLK    256     // bin grid (R4-proven)
#define BUFCAP    64      // per-bucket LDS chunk buffer (entries, R4-proven)
#define HISTBLK   512

typedef float nfloat4 __attribute__((ext_vector_type(4)));   // native vec for nontemporal builtins

__device__ inline float bf_lo(unsigned int u) {
    union { unsigned int i; float f; } v; v.i = u << 16; return v.f;
}
__device__ inline float bf_hi(unsigned int u) {
    union { unsigned int i; float f; } v; v.i = u & 0xFFFF0000u; return v.f;
}
__device__ inline unsigned short f2bf(float f) {
    union { float f; unsigned int i; } v; v.f = f;
    unsigned int r = (v.i + 0x7FFFu + ((v.i >> 16) & 1u)) >> 16;  // RNE
    return (unsigned short)r;
}
__device__ inline void nt_store4(float4 v, float4* p) {
    nfloat4 nv; nv.x = v.x; nv.y = v.y; nv.z = v.z; nv.w = v.w;
    __builtin_nontemporal_store(nv, (nfloat4*)p);
}
__device__ inline void acc8(float* s, uint4 v) {
    s[0] += bf_lo(v.x); s[1] += bf_hi(v.x); s[2] += bf_lo(v.y); s[3] += bf_hi(v.y);
    s[4] += bf_lo(v.z); s[5] += bf_hi(v.z); s[6] += bf_lo(v.w); s[7] += bf_hi(v.w);
}

// out[row,0:128] = feature[row]; featbf[row] = bf16(feature[row]); block 0 zeroes bcnt+done
__global__ void copy_cast_kernel(const float4* __restrict__ feat4, float* __restrict__ out,
                                 ushort4* __restrict__ featbf, unsigned int* __restrict__ bcnt,
                                 int n) {
    if (blockIdx.x == 0) {
        if (threadIdx.x < NB) bcnt[threadIdx.x] = 0u;
        if (threadIdx.x == 0) bcnt[NB] = 0u;       // done counter (R7 bug: was never zeroed)
    }
    int idx = blockIdx.x * blockDim.x + threadIdx.x;
    int row = idx >> 5;
    int c = idx & 31;
    if (row >= n) return;
    float4 v = feat4[(long long)row * 32 + c];
    nt_store4(v, (float4*)(out + (long long)row * OUTW) + c);
    ushort4 b; b.x = f2bf(v.x); b.y = f2bf(v.y); b.z = f2bf(v.z); b.w = f2bf(v.w);
    featbf[(long long)row * 32 + c] = b;
}

// fp32-fallback copy (no bf16 table); also zeroes bcnt+done
__global__ void copy_feat_kernel(const float4* __restrict__ feat4, float* __restrict__ out,
                                 unsigned int* __restrict__ bcnt, int n) {
    if (blockIdx.x == 0) {
        if (threadIdx.x < NB) bcnt[threadIdx.x] = 0u;
        if (threadIdx.x == 0) bcnt[NB] = 0u;
    }
    int idx = blockIdx.x * blockDim.x + threadIdx.x;
    int row = idx >> 5;
    int c = idx & 31;
    if (row >= n) return;
    ((float4*)(out + (long long)row * OUTW))[c] = feat4[(long long)row * 32 + c];
}

// ---------------- bucketed CSR build ----------------

// Pass 1: bucket histogram (LDS-staged, int4 loads) + fused last-block exclusive scan.
// done = bcnt + NB (zeroed by copy kernel).
__global__ __launch_bounds__(256) void hist_kernel(const int* __restrict__ dst,
                                                   unsigned int* __restrict__ bcnt,
                                                   unsigned int* __restrict__ base,
                                                   unsigned int* __restrict__ tail, int E) {
    __shared__ unsigned int h[NB];
    __shared__ int lastflag;
    int t = threadIdx.x;
    h[t] = 0u;
    __syncthreads();
    int E4 = E >> 2;
    const int4* d4 = (const int4*)dst;
    for (int i = blockIdx.x * blockDim.x + t; i < E4; i += gridDim.x * blockDim.x) {
        int4 v = d4[i];
        atomicAdd(&h[(unsigned int)v.x / NPB], 1u);
        atomicAdd(&h[(unsigned int)v.y / NPB], 1u);
        atomicAdd(&h[(unsigned int)v.z / NPB], 1u);
        atomicAdd(&h[(unsigned int)v.w / NPB], 1u);
    }
    for (int e = (E4 << 2) + blockIdx.x * blockDim.x + t; e < E; e += gridDim.x * blockDim.x)
        atomicAdd(&h[(unsigned int)dst[e] / NPB], 1u);
    __syncthreads();
    if (h[t]) atomicAdd(&bcnt[t], h[t]);
    __threadfence();
    __syncthreads();
    if (t == 0) {
        unsigned int r = atomicAdd(&bcnt[NB], 1u);   // done counter
        lastflag = (r == gridDim.x - 1) ? 1 : 0;
    }
    __syncthreads();
    if (!lastflag) return;
    __threadfence();
    // coherent read of final counts
    unsigned int v = atomicAdd(&bcnt[t], 0u);
    h[t] = v;
    __syncthreads();
    for (int d = 1; d < NB; d <<= 1) {
        unsigned int x = (t >= d) ? h[t - d] : 0u;
        __syncthreads();
        h[t] += x;
        __syncthreads();
    }
    unsigned int excl = (t > 0) ? h[t - 1] : 0u;
    base[t] = excl;
    tail[t] = excl;
    if (t == NB - 1) base[NB] = h[t];
}

// Pass 3: bin edges into bucket regions. 1024 threads, 4 edges/thread via int4.
// Per-bucket LDS chunks flushed as full 64B lines (tail atomics claim 16 slots at once).
// Rare overflow -> direct single write (correct for any distribution).
// entry = (src << 9) | (dst - bucket*NPB)   [src<2^17, dst_low<512]
__global__ __launch_bounds__(BINW) void bin_kernel(const int* __restrict__ src,
                                                   const int* __restrict__ dst,
                                                   unsigned int* __restrict__ tail,
                                                   unsigned int* __restrict__ binned, int E) {
    __shared__ unsigned int cnt[NB];
    __shared__ unsigned int buf[NB][BUFCAP];
    int t = threadIdx.x;
    if (t < NB) cnt[t] = 0u;
    __syncthreads();
    int chunk = ((E + (int)gridDim.x * 4 - 1) / ((int)gridDim.x * 4)) * 4;  // multiple of 4
    int s0 = blockIdx.x * chunk;
    int s1 = s0 + chunk; if (s1 > E) s1 = E;
    bool vec_ok = ((E & 3) == 0);   // dst = edge_index + E stays 16B-aligned

    for (int base_e = s0; base_e < s1; base_e += BINW * 4) {
        int e0 = base_e + t * 4;
        int4 d4, r4;
        int nvalid = 0;
        if (vec_ok && e0 + 3 < s1) {
            d4 = *(const int4*)(dst + e0);
            r4 = *(const int4*)(src + e0);
            nvalid = 4;
        } else {
            int tmp_d[4] = {0, 0, 0, 0}, tmp_s[4] = {0, 0, 0, 0};
            for (int j = 0; j < 4; ++j) {
                if (e0 + j < s1) { tmp_d[j] = dst[e0 + j]; tmp_s[j] = src[e0 + j]; nvalid = j + 1; }
            }
            d4 = make_int4(tmp_d[0], tmp_d[1], tmp_d[2], tmp_d[3]);
            r4 = make_int4(tmp_s[0], tmp_s[1], tmp_s[2], tmp_s[3]);
        }
        int dv[4] = {d4.x, d4.y, d4.z, d4.w};
        int sv[4] = {r4.x, r4.y, r4.z, r4.w};
        #pragma unroll
        for (int j = 0; j < 4; ++j) {
            if (j < nvalid) {
                unsigned int d = (unsigned int)dv[j];
                unsigned int b = d / NPB;
                unsigned int entry = ((unsigned int)sv[j] << 9) | (d - b * NPB);
                unsigned int pos = atomicAdd(&cnt[b], 1u);
                if (pos < BUFCAP) buf[b][pos] = entry;
                else { unsigned int g = atomicAdd(&tail[b], 1u); binned[g] = entry; }
            }
        }
        __syncthreads();
        if (t < NB) {
            unsigned int c = cnt[t]; if (c > BUFCAP) c = BUFCAP;
            unsigned int nch = c >> 4;
            if (nch) {
                unsigned int nfl = nch << 4;
                unsigned int g = atomicAdd(&tail[t], nfl);
                if ((g & 3u) == 0u) {
                    uint4* p = (uint4*)(binned + g);
                    for (unsigned int j = 0; j < nch * 4u; ++j)
                        p[j] = make_uint4(buf[t][4 * j], buf[t][4 * j + 1],
                                          buf[t][4 * j + 2], buf[t][4 * j + 3]);
                } else {
                    for (unsigned int j = 0; j < nfl; ++j) binned[g + j] = buf[t][j];
                }
                unsigned int rem = c - nfl;
                for (unsigned int j = 0; j < rem; ++j) buf[t][j] = buf[t][nfl + j];
                cnt[t] = rem;
            } else {
                cnt[t] = c;
            }
        }
        __syncthreads();
    }
    if (t < NB) {
        unsigned int c = cnt[t]; if (c > BUFCAP) c = BUFCAP;
        if (c) {
            unsigned int g = atomicAdd(&tail[t], c);
            for (unsigned int j = 0; j < c; ++j) binned[g + j] = buf[t][j];
        }
    }
}

// Pass 4: per-bucket exact counting sort; entries staged in LDS on first read
// (single global pass); coalesced writeback of edge_src; writes offsets
// (inclusive end, same convention as gather) and deg_inv.
__global__ __launch_bounds__(512) void bucket_csr_kernel(const unsigned int* __restrict__ base,
                                                         const unsigned int* __restrict__ binned,
                                                         unsigned int* __restrict__ offsets,
                                                         float* __restrict__ deg_inv,
                                                         int* __restrict__ edge_src) {
    __shared__ unsigned int ncnt[NPB + 1];   // counters, reused as running placement offsets
    __shared__ unsigned int scanA[512];
    __shared__ unsigned int stage_in[BCAP];  // raw entries (count pass)
    __shared__ unsigned int stage[BCAP];     // placed srcs
    int b = blockIdx.x, t = threadIdx.x;     // t in 0..511
    unsigned int beg = base[b], end = base[b + 1];
    unsigned int n = end - beg;
    bool fits = (n <= BCAP);

    if (t < NPB) ncnt[t] = 0u;
    __syncthreads();
    if (fits) {
        for (unsigned int i = t; i < n; i += 512) {
            unsigned int e = binned[beg + i];
            stage_in[i] = e;
            atomicAdd(&ncnt[e & 511u], 1u);
        }
    } else {
        for (unsigned int i = t; i < n; i += 512) {
            unsigned int e = binned[beg + i];
            atomicAdd(&ncnt[e & 511u], 1u);
        }
    }
    __syncthreads();
    scanA[t] = (t < NPB) ? ncnt[t] : 0u;
    __syncthreads();
    for (int d = 1; d < 512; d <<= 1) {
        unsigned int x = (t >= d) ? scanA[t - d] : 0u;
        __syncthreads();
        scanA[t] += x;
        __syncthreads();
    }
    int gbase = b * NPB;
    if (t < NPB) {
        unsigned int incl = scanA[t];
        unsigned int excl = (t > 0) ? scanA[t - 1] : 0u;
        int g = gbase + t;
        if (g < N_NODES) {
            offsets[g] = beg + incl;
            unsigned int dg = incl - excl;
            deg_inv[g] = (dg > 0u) ? (1.0f / (float)dg) : 0.0f;
        }
        ncnt[t] = excl;
    }
    __syncthreads();
    if (fits) {
        for (unsigned int i = t; i < n; i += 512) {
            unsigned int e = stage_in[i];
            unsigned int pos = atomicAdd(&ncnt[e & 511u], 1u);
            stage[pos] = e >> 9;
        }
        __syncthreads();
        for (unsigned int i = t; i < n; i += 512)
            edge_src[beg + i] = (int)stage[i];
    } else {
        for (unsigned int i = t; i < n; i += 512) {
            unsigned int e = binned[beg + i];
            unsigned int pos = atomicAdd(&ncnt[e & 511u], 1u);
            edge_src[beg + pos] = (int)(e >> 9);
        }
    }
}

// ---------------- gather ----------------

// high-degree fallback: direct index loads, one node
__device__ void gather_node_direct(float* s, unsigned int beg, unsigned int end,
                                   const int* __restrict__ edge_src,
                                   const uint4* __restrict__ table, int sub, int c) {
    unsigned int k = beg;
    for (; k + 16 <= end; k += 16) {
        int sA = edge_src[k + sub];
        int sB = edge_src[k + 4 + sub];
        int sC = edge_src[k + 8 + sub];
        int sD = edge_src[k + 12 + sub];
        uint4 vA = table[(long long)sA * 16 + c];
        uint4 vB = table[(long long)sB * 16 + c];
        uint4 vC = table[(long long)sC * 16 + c];
        uint4 vD = table[(long long)sD * 16 + c];
        acc8(s, vA); acc8(s, vB); acc8(s, vC); acc8(s, vD);
    }
    for (; k < end; k += 4) {
        unsigned int e = k + sub;
        if (e < end) {
            int sA = edge_src[e];
            uint4 vA = table[(long long)sA * 16 + c];
            acc8(s, vA);
        }
    }
}

// bf16-table gather: one wave per TWO nodes; quarter-wave (16 lanes) per edge.
// Both nodes' index vectors loaded coalesced up-front; fused main loop keeps
// up to 8 independent row loads in flight (4 per node) -> 2x pipeline depth.
__global__ __launch_bounds__(256) void gather_mean_bf16_kernel(
        const unsigned int* __restrict__ offsets,
        const int* __restrict__ edge_src,
        const uint4* __restrict__ table,        // bf16 rows, 16 uint4 per row
        float* __restrict__ h_out, int out_stride,
        ushort4* __restrict__ bf_out,           // may be null
        const float* __restrict__ deg_inv, int n) {
    int wv = (blockIdx.x * blockDim.x + threadIdx.x) >> 6;
    int n0raw = wv * 2;
    if (n0raw >= n) return;
    int node0 = __builtin_amdgcn_readfirstlane(n0raw);   // wave-uniform -> scalar loads
    int node1 = node0 + 1;
    bool has1 = (node1 < n);
    int lane = threadIdx.x & 63;
    int sub = lane >> 4;     // 0..3 : which edge of the group of 4
    int c = lane & 15;       // 16B chunk within row
    unsigned int beg0 = (node0 > 0) ? offsets[node0 - 1] : 0u;
    unsigned int end0 = offsets[node0];
    unsigned int end1 = has1 ? offsets[node1] : end0;
    int deg0 = (int)(end0 - beg0);
    int deg1 = (int)(end1 - end0);    // beg1 == end0

    float a0[8] = {0.f, 0.f, 0.f, 0.f, 0.f, 0.f, 0.f, 0.f};
    float a1[8] = {0.f, 0.f, 0.f, 0.f, 0.f, 0.f, 0.f, 0.f};

    if (deg0 <= 64 && deg1 <= 64) {
        // coalesced 256B index loads, both in flight
        int idx0 = (lane < deg0) ? edge_src[beg0 + lane] : 0;
        int idx1 = (has1 && lane < deg1) ? edge_src[end0 + lane] : 0;
        int dmax = (deg0 > deg1) ? deg0 : deg1;
        for (int k = 0; k < dmax; k += 16) {
            #pragma unroll
            for (int q = 0; q < 4; ++q) {
                int e = k + q * 4 + sub;
                int s = __shfl(idx0, (e < 64) ? e : 63, 64);   // shfl outside guard
                if (e < deg0) {
                    uint4 v = table[(long long)s * 16 + c];
                    acc8(a0, v);
                }
            }
            #pragma unroll
            for (int q = 0; q < 4; ++q) {
                int e = k + q * 4 + sub;
                int s = __shfl(idx1, (e < 64) ? e : 63, 64);
                if (e < deg1) {
                    uint4 v = table[(long long)s * 16 + c];
                    acc8(a1, v);
                }
            }
        }
    } else {
        gather_node_direct(a0, beg0, end0, edge_src, table, sub, c);
        if (has1) gather_node_direct(a1, end0, end1, edge_src, table, sub, c);
    }

    // combine the 4 subgroups for both nodes
    #pragma unroll
    for (int j = 0; j < 8; ++j) {
        a0[j] += __shfl_xor(a0[j], 16, 64);
        a1[j] += __shfl_xor(a1[j], 16, 64);
        a0[j] += __shfl_xor(a0[j], 32, 64);
        a1[j] += __shfl_xor(a1[j], 32, 64);
    }
    if (sub == 0) {
        float inv0 = deg_inv[node0];
        float4 r0 = {a0[0] * inv0, a0[1] * inv0, a0[2] * inv0, a0[3] * inv0};
        float4 r1 = {a0[4] * inv0, a0[5] * inv0, a0[6] * inv0, a0[7] * inv0};
        float4* orow = (float4*)(h_out + (long long)node0 * out_stride);
        nt_store4(r0, orow + c * 2);
        nt_store4(r1, orow + c * 2 + 1);
        if (bf_out) {
            ushort4 b0; b0.x = f2bf(r0.x); b0.y = f2bf(r0.y); b0.z = f2bf(r0.z); b0.w = f2bf(r0.w);
            ushort4 b1; b1.x = f2bf(r1.x); b1.y = f2bf(r1.y); b1.z = f2bf(r1.z); b1.w = f2bf(r1.w);
            bf_out[(long long)node0 * 32 + c * 2]     = b0;
            bf_out[(long long)node0 * 32 + c * 2 + 1] = b1;
        }
        if (has1) {
            float inv1 = deg_inv[node1];
            float4 r2 = {a1[0] * inv1, a1[1] * inv1, a1[2] * inv1, a1[3] * inv1};
            float4 r3 = {a1[4] * inv1, a1[5] * inv1, a1[6] * inv1, a1[7] * inv1};
            float4* orow1 = (float4*)(h_out + (long long)node1 * out_stride);
            nt_store4(r2, orow1 + c * 2);
            nt_store4(r3, orow1 + c * 2 + 1);
            if (bf_out) {
                ushort4 b2; b2.x = f2bf(r2.x); b2.y = f2bf(r2.y); b2.z = f2bf(r2.z); b2.w = f2bf(r2.w);
                ushort4 b3; b3.x = f2bf(r3.x); b3.y = f2bf(r3.y); b3.z = f2bf(r3.z); b3.w = f2bf(r3.w);
                bf_out[(long long)node1 * 32 + c * 2]     = b2;
                bf_out[(long long)node1 * 32 + c * 2 + 1] = b3;
            }
        }
    }
}

// fp32 fallback gather (half-wave per edge, float4 per lane)
__global__ __launch_bounds__(256) void gather_mean_kernel(const unsigned int* __restrict__ offsets,
                                   const int* __restrict__ edge_src,
                                   const float* __restrict__ h_in, int in_stride,
                                   float* __restrict__ h_out, int out_stride,
                                   const float* __restrict__ deg_inv, int n) {
    int wave = (blockIdx.x * blockDim.x + threadIdx.x) >> 6;
    if (wave >= n) return;
    int lane = threadIdx.x & 63;
    int half = lane >> 5;
    int c = lane & 31;
    unsigned int beg = (wave > 0) ? offsets[wave - 1] : 0u;
    unsigned int end = offsets[wave];
    const float4* hp = (const float4*)h_in;
    int s4 = in_stride >> 2;

    float ax = 0.f, ay = 0.f, az = 0.f, aw = 0.f;
    unsigned int k = beg;
    for (; k + 4 <= end; k += 4) {
        int sA = edge_src[k + half];
        int sB = edge_src[k + 2 + half];
        float4 vA = hp[(long long)sA * s4 + c];
        float4 vB = hp[(long long)sB * s4 + c];
        ax += vA.x + vB.x; ay += vA.y + vB.y; az += vA.z + vB.z; aw += vA.w + vB.w;
    }
    if (k + 2 <= end) {
        int sA = edge_src[k + half];
        float4 vA = hp[(long long)sA * s4 + c];
        ax += vA.x; ay += vA.y; az += vA.z; aw += vA.w;
        k += 2;
    }
    if (k + half < end) {
        int sA = edge_src[k + half];
        float4 vA = hp[(long long)sA * s4 + c];
        ax += vA.x; ay += vA.y; az += vA.z; aw += vA.w;
    }
    ax += __shfl_xor(ax, 32, 64);
    ay += __shfl_xor(ay, 32, 64);
    az += __shfl_xor(az, 32, 64);
    aw += __shfl_xor(aw, 32, 64);
    if (half == 0) {
        float inv = deg_inv[wave];
        float4 r = {ax * inv, ay * inv, az * inv, aw * inv};
        ((float4*)(h_out + (long long)wave * out_stride))[c] = r;
    }
}

extern "C" void kernel_launch(void* const* d_in, const int* in_sizes, int n_in,
                              void* d_out, int out_size, void* d_ws, size_t ws_size,
                              hipStream_t stream) {
    const float* feature = (const float*)d_in[0];
    const int* edge_index = (const int*)d_in[1];
    const int E = in_sizes[1] / 2;         // 1,600,000
    const int* src = edge_index;           // edge_index[0, :]
    const int* dst = edge_index + E;       // edge_index[1, :]

    float* out = (float*)d_out;

    // ws: deg_inv | offsets | bcnt(+done) | bbase(+pad) | btail | edge_src | featbf | h1bf
    // binned[E] aliases h1bf (dead until gather layer 1)
    char* ws = (char*)d_ws;
    float*        deg_inv  = (float*)ws;         ws += (size_t)N_NODES * 4;
    unsigned int* offsets  = (unsigned int*)ws;  ws += (size_t)N_NODES * 4;
    unsigned int* bcnt     = (unsigned int*)ws;  ws += (NB + 8) * 4;   // NB counters + done
    unsigned int* bbase    = (unsigned int*)ws;  ws += (NB + 4) * 4;   // 257 used, padded to 16B
    unsigned int* btail    = (unsigned int*)ws;  ws += NB * 4;
    int*          edge_src = (int*)ws;           ws += (size_t)E * 4;
    char*         tail_ws  = ws;
    ushort4*      featbf   = (ushort4*)ws;       ws += (size_t)N_NODES * DFEAT * 2;
    ushort4*      h1bf     = (ushort4*)ws;       ws += (size_t)N_NODES * DFEAT * 2;
    size_t need_bf = (size_t)(ws - (char*)d_ws);
    bool use_bf16 = (ws_size >= need_bf);
    unsigned int* binned = use_bf16 ? (unsigned int*)h1bf : (unsigned int*)tail_ws;

    // out[:,0:128] = feature (+ bf16 cast); zeroes bcnt+done
    {
        int nthreads = N_NODES * 32;
        if (use_bf16)
            copy_cast_kernel<<<(nthreads + 255) / 256, 256, 0, stream>>>((const float4*)feature, out, featbf, bcnt, N_NODES);
        else
            copy_feat_kernel<<<(nthreads + 255) / 256, 256, 0, stream>>>((const float4*)feature, out, bcnt, N_NODES);
    }

    // bucketed CSR build (hist has fused last-block scan -> bbase/btail)
    hist_kernel<<<HISTBLK, 256, 0, stream>>>(dst, bcnt, bbase, btail, E);
    bin_kernel<<<BINBLK, BINW, 0, stream>>>(src, dst, btail, binned, E);
    bucket_csr_kernel<<<NB, 512, 0, stream>>>(bbase, binned, offsets, deg_inv, edge_src);

    if (use_bf16) {
        long long waves = (N_NODES + 1) / 2;          // 2 nodes per wave
        int blocks = (int)((waves * 64 + 255) / 256);
        // layer 1: featbf -> out[:,128:256] (+ h1bf; overwrites binned, which is dead now)
        gather_mean_bf16_kernel<<<blocks, 256, 0, stream>>>(offsets, edge_src,
                                                            (const uint4*)featbf,
                                                            out + DFEAT, OUTW,
                                                            h1bf, deg_inv, N_NODES);
        // layer 2: h1bf -> out[:,256:384]
        gather_mean_bf16_kernel<<<blocks, 256, 0, stream>>>(offsets, edge_src,
                                                            (const uint4*)h1bf,
                                                            out + 2 * DFEAT, OUTW,
                                                            (ushort4*)nullptr, deg_inv, N_NODES);
    } else {
        long long threads = (long long)N_NODES * 64;
        int blocks = (int)((threads + 255) / 256);
        gather_mean_kernel<<<blocks, 256, 0, stream>>>(offsets, edge_src,
                                                       feature, DFEAT,
                                                       out + DFEAT, OUTW,
                                                       deg_inv, N_NODES);
        gather_mean_kernel<<<blocks, 256, 0, stream>>>(offsets, edge_src,
                                                       out + DFEAT, OUTW,
                                                       out + 2 * DFEAT, OUTW,
                                                       deg_inv, N_NODES);
    }
}

// Round 9
// 418.479 us; speedup vs baseline: 1.0067x; 1.0067x over previous
//
#include <hip/hip_runtime.h>

#define N_NODES   100000
#define DFEAT     128
#define OUTW      384     // 3 * 128
#define NB        256     // dst buckets
#define NPB       391     // nodes per bucket (256*391 = 100096 >= 100000)
#define BCAP      8192    // per-bucket LDS staging capacity (mean 6250, sigma ~79)
#define BINW      1024    // threads per bin block
#define BINBLK    256     // bin grid (R4-proven)
#define BUFCAP    64      // per-bucket LDS chunk buffer (entries, R4-proven)
#define HISTBLK   512

typedef float nfloat4 __attribute__((ext_vector_type(4)));   // native vec for nontemporal builtins

__device__ inline float bf_lo(unsigned int u) {
    union { unsigned int i; float f; } v; v.i = u << 16; return v.f;
}
__device__ inline float bf_hi(unsigned int u) {
    union { unsigned int i; float f; } v; v.i = u & 0xFFFF0000u; return v.f;
}
__device__ inline unsigned short f2bf(float f) {
    union { float f; unsigned int i; } v; v.f = f;
    unsigned int r = (v.i + 0x7FFFu + ((v.i >> 16) & 1u)) >> 16;  // RNE
    return (unsigned short)r;
}
__device__ inline void nt_store4(float4 v, float4* p) {
    nfloat4 nv; nv.x = v.x; nv.y = v.y; nv.z = v.z; nv.w = v.w;
    __builtin_nontemporal_store(nv, (nfloat4*)p);
}

// Fused prep: blocks [0,CB) copy feature -> out[:,0:128] (+ bf16 cast);
// blocks [CB, CB+HISTBLK) histogram dst buckets + decoupled last-block scan
// -> bbase/btail.  bcnt[0..NB] zeroed by a prior 1KB memset.
__global__ __launch_bounds__(256) void prep_kernel(
        const float4* __restrict__ feat4, float* __restrict__ out,
        ushort4* __restrict__ featbf,                 // may be null (fp32 fallback)
        const int* __restrict__ dst,
        unsigned int* __restrict__ bcnt,
        unsigned int* __restrict__ base,
        unsigned int* __restrict__ tail,
        int n, int E, int CB) {
    __shared__ unsigned int h[NB];
    __shared__ int lastflag;
    if ((int)blockIdx.x < CB) {
        // ---- copy/cast path ----
        int idx = blockIdx.x * 256 + threadIdx.x;
        int row = idx >> 5;
        int c = idx & 31;
        if (row >= n) return;
        float4 v = feat4[(long long)row * 32 + c];
        nt_store4(v, (float4*)(out + (long long)row * OUTW) + c);
        if (featbf) {
            ushort4 b; b.x = f2bf(v.x); b.y = f2bf(v.y); b.z = f2bf(v.z); b.w = f2bf(v.w);
            featbf[(long long)row * 32 + c] = b;
        }
        return;
    }
    // ---- histogram path ----
    int hb = blockIdx.x - CB;                       // 0..HISTBLK-1
    int t = threadIdx.x;
    h[t] = 0u;
    __syncthreads();
    int E4 = E >> 2;
    const int4* d4 = (const int4*)dst;
    for (int i = hb * 256 + t; i < E4; i += HISTBLK * 256) {
        int4 v = d4[i];
        atomicAdd(&h[(unsigned int)v.x / NPB], 1u);
        atomicAdd(&h[(unsigned int)v.y / NPB], 1u);
        atomicAdd(&h[(unsigned int)v.z / NPB], 1u);
        atomicAdd(&h[(unsigned int)v.w / NPB], 1u);
    }
    for (int e = (E4 << 2) + hb * 256 + t; e < E; e += HISTBLK * 256)
        atomicAdd(&h[(unsigned int)dst[e] / NPB], 1u);
    __syncthreads();
    if (h[t]) atomicAdd(&bcnt[t], h[t]);
    __threadfence();
    __syncthreads();
    if (t == 0) {
        unsigned int r = atomicAdd(&bcnt[NB], 1u);   // done counter
        lastflag = (r == HISTBLK - 1) ? 1 : 0;
    }
    __syncthreads();
    if (!lastflag) return;
    __threadfence();
    unsigned int v = atomicAdd(&bcnt[t], 0u);        // coherent read of final counts
    h[t] = v;
    __syncthreads();
    for (int d = 1; d < NB; d <<= 1) {
        unsigned int x = (t >= d) ? h[t - d] : 0u;
        __syncthreads();
        h[t] += x;
        __syncthreads();
    }
    unsigned int excl = (t > 0) ? h[t - 1] : 0u;
    base[t] = excl;
    tail[t] = excl;
    if (t == NB - 1) base[NB] = h[t];
}

// Pass 2: bin edges into bucket regions. 1024 threads, 4 edges/thread via int4.
// Per-bucket LDS chunks flushed as full 64B lines (tail atomics claim 16 slots at once).
// Rare overflow -> direct single write (correct for any distribution).
// entry = (src << 9) | (dst - bucket*NPB)   [src<2^17, dst_low<512]
__global__ __launch_bounds__(BINW) void bin_kernel(const int* __restrict__ src,
                                                   const int* __restrict__ dst,
                                                   unsigned int* __restrict__ tail,
                                                   unsigned int* __restrict__ binned, int E) {
    __shared__ unsigned int cnt[NB];
    __shared__ unsigned int buf[NB][BUFCAP];
    int t = threadIdx.x;
    if (t < NB) cnt[t] = 0u;
    __syncthreads();
    int chunk = ((E + (int)gridDim.x * 4 - 1) / ((int)gridDim.x * 4)) * 4;  // multiple of 4
    int s0 = blockIdx.x * chunk;
    int s1 = s0 + chunk; if (s1 > E) s1 = E;
    bool vec_ok = ((E & 3) == 0);   // dst = edge_index + E stays 16B-aligned

    for (int base_e = s0; base_e < s1; base_e += BINW * 4) {
        int e0 = base_e + t * 4;
        int4 d4, r4;
        int nvalid = 0;
        if (vec_ok && e0 + 3 < s1) {
            d4 = *(const int4*)(dst + e0);
            r4 = *(const int4*)(src + e0);
            nvalid = 4;
        } else {
            int tmp_d[4] = {0, 0, 0, 0}, tmp_s[4] = {0, 0, 0, 0};
            for (int j = 0; j < 4; ++j) {
                if (e0 + j < s1) { tmp_d[j] = dst[e0 + j]; tmp_s[j] = src[e0 + j]; nvalid = j + 1; }
            }
            d4 = make_int4(tmp_d[0], tmp_d[1], tmp_d[2], tmp_d[3]);
            r4 = make_int4(tmp_s[0], tmp_s[1], tmp_s[2], tmp_s[3]);
        }
        int dv[4] = {d4.x, d4.y, d4.z, d4.w};
        int sv[4] = {r4.x, r4.y, r4.z, r4.w};
        #pragma unroll
        for (int j = 0; j < 4; ++j) {
            if (j < nvalid) {
                unsigned int d = (unsigned int)dv[j];
                unsigned int b = d / NPB;
                unsigned int entry = ((unsigned int)sv[j] << 9) | (d - b * NPB);
                unsigned int pos = atomicAdd(&cnt[b], 1u);
                if (pos < BUFCAP) buf[b][pos] = entry;
                else { unsigned int g = atomicAdd(&tail[b], 1u); binned[g] = entry; }
            }
        }
        __syncthreads();
        if (t < NB) {
            unsigned int c = cnt[t]; if (c > BUFCAP) c = BUFCAP;
            unsigned int nch = c >> 4;
            if (nch) {
                unsigned int nfl = nch << 4;
                unsigned int g = atomicAdd(&tail[t], nfl);
                if ((g & 3u) == 0u) {
                    uint4* p = (uint4*)(binned + g);
                    for (unsigned int j = 0; j < nch * 4u; ++j)
                        p[j] = make_uint4(buf[t][4 * j], buf[t][4 * j + 1],
                                          buf[t][4 * j + 2], buf[t][4 * j + 3]);
                } else {
                    for (unsigned int j = 0; j < nfl; ++j) binned[g + j] = buf[t][j];
                }
                unsigned int rem = c - nfl;
                for (unsigned int j = 0; j < rem; ++j) buf[t][j] = buf[t][nfl + j];
                cnt[t] = rem;
            } else {
                cnt[t] = c;
            }
        }
        __syncthreads();
    }
    if (t < NB) {
        unsigned int c = cnt[t]; if (c > BUFCAP) c = BUFCAP;
        if (c) {
            unsigned int g = atomicAdd(&tail[t], c);
            for (unsigned int j = 0; j < c; ++j) binned[g + j] = buf[t][j];
        }
    }
}

// Pass 3: per-bucket exact counting sort; entries staged in LDS on first read
// (single global pass); coalesced writeback of edge_src; writes offsets
// (inclusive end, same convention as gather) and deg_inv.
__global__ __launch_bounds__(512) void bucket_csr_kernel(const unsigned int* __restrict__ base,
                                                         const unsigned int* __restrict__ binned,
                                                         unsigned int* __restrict__ offsets,
                                                         float* __restrict__ deg_inv,
                                                         int* __restrict__ edge_src) {
    __shared__ unsigned int ncnt[NPB + 1];   // counters, reused as running placement offsets
    __shared__ unsigned int scanA[512];
    __shared__ unsigned int stage_in[BCAP];  // raw entries (count pass)
    __shared__ unsigned int stage[BCAP];     // placed srcs
    int b = blockIdx.x, t = threadIdx.x;     // t in 0..511
    unsigned int beg = base[b], end = base[b + 1];
    unsigned int n = end - beg;
    bool fits = (n <= BCAP);

    if (t < NPB) ncnt[t] = 0u;
    __syncthreads();
    if (fits) {
        for (unsigned int i = t; i < n; i += 512) {
            unsigned int e = binned[beg + i];
            stage_in[i] = e;
            atomicAdd(&ncnt[e & 511u], 1u);
        }
    } else {
        for (unsigned int i = t; i < n; i += 512) {
            unsigned int e = binned[beg + i];
            atomicAdd(&ncnt[e & 511u], 1u);
        }
    }
    __syncthreads();
    scanA[t] = (t < NPB) ? ncnt[t] : 0u;
    __syncthreads();
    for (int d = 1; d < 512; d <<= 1) {
        unsigned int x = (t >= d) ? scanA[t - d] : 0u;
        __syncthreads();
        scanA[t] += x;
        __syncthreads();
    }
    int gbase = b * NPB;
    if (t < NPB) {
        unsigned int incl = scanA[t];
        unsigned int excl = (t > 0) ? scanA[t - 1] : 0u;
        int g = gbase + t;
        if (g < N_NODES) {
            offsets[g] = beg + incl;
            unsigned int dg = incl - excl;
            deg_inv[g] = (dg > 0u) ? (1.0f / (float)dg) : 0.0f;
        }
        ncnt[t] = excl;
    }
    __syncthreads();
    if (fits) {
        for (unsigned int i = t; i < n; i += 512) {
            unsigned int e = stage_in[i];
            unsigned int pos = atomicAdd(&ncnt[e & 511u], 1u);
            stage[pos] = e >> 9;
        }
        __syncthreads();
        for (unsigned int i = t; i < n; i += 512)
            edge_src[beg + i] = (int)stage[i];
    } else {
        for (unsigned int i = t; i < n; i += 512) {
            unsigned int e = binned[beg + i];
            unsigned int pos = atomicAdd(&ncnt[e & 511u], 1u);
            edge_src[beg + pos] = (int)(e >> 9);
        }
    }
}

// ---------------- gather (R4-proven exact version) ----------------

// bf16-table gather: one wave per node, quarter-wave (16 lanes) per edge.
// Main loop: 16 edges/iter -> 4 independent uint4 row loads in flight per lane.
__global__ __launch_bounds__(256) void gather_mean_bf16_kernel(
        const unsigned int* __restrict__ offsets,
        const int* __restrict__ edge_src,
        const uint4* __restrict__ table,        // bf16 rows, 16 uint4 per row
        float* __restrict__ h_out, int out_stride,
        ushort4* __restrict__ bf_out,           // may be null
        const float* __restrict__ deg_inv, int n) {
    int wv = (blockIdx.x * blockDim.x + threadIdx.x) >> 6;
    if (wv >= n) return;
    int wave = __builtin_amdgcn_readfirstlane(wv);   // wave-uniform -> scalar loads
    int lane = threadIdx.x & 63;
    int sub = lane >> 4;     // 0..3 : which edge of the group of 4
    int c = lane & 15;       // 16B chunk within row
    unsigned int beg = (wave > 0) ? offsets[wave - 1] : 0u;
    unsigned int end = offsets[wave];

    float s0 = 0.f, s1 = 0.f, s2 = 0.f, s3 = 0.f, s4 = 0.f, s5 = 0.f, s6 = 0.f, s7 = 0.f;
    unsigned int k = beg;
    for (; k + 16 <= end; k += 16) {
        int sA = edge_src[k + sub];
        int sB = edge_src[k + 4 + sub];
        int sC = edge_src[k + 8 + sub];
        int sD = edge_src[k + 12 + sub];
        uint4 vA = table[(long long)sA * 16 + c];
        uint4 vB = table[(long long)sB * 16 + c];
        uint4 vC = table[(long long)sC * 16 + c];
        uint4 vD = table[(long long)sD * 16 + c];
        s0 += bf_lo(vA.x); s1 += bf_hi(vA.x); s2 += bf_lo(vA.y); s3 += bf_hi(vA.y);
        s4 += bf_lo(vA.z); s5 += bf_hi(vA.z); s6 += bf_lo(vA.w); s7 += bf_hi(vA.w);
        s0 += bf_lo(vB.x); s1 += bf_hi(vB.x); s2 += bf_lo(vB.y); s3 += bf_hi(vB.y);
        s4 += bf_lo(vB.z); s5 += bf_hi(vB.z); s6 += bf_lo(vB.w); s7 += bf_hi(vB.w);
        s0 += bf_lo(vC.x); s1 += bf_hi(vC.x); s2 += bf_lo(vC.y); s3 += bf_hi(vC.y);
        s4 += bf_lo(vC.z); s5 += bf_hi(vC.z); s6 += bf_lo(vC.w); s7 += bf_hi(vC.w);
        s0 += bf_lo(vD.x); s1 += bf_hi(vD.x); s2 += bf_lo(vD.y); s3 += bf_hi(vD.y);
        s4 += bf_lo(vD.z); s5 += bf_hi(vD.z); s6 += bf_lo(vD.w); s7 += bf_hi(vD.w);
    }
    if (k + 8 <= end) {
        int sA = edge_src[k + sub];
        int sB = edge_src[k + 4 + sub];
        uint4 vA = table[(long long)sA * 16 + c];
        uint4 vB = table[(long long)sB * 16 + c];
        s0 += bf_lo(vA.x); s1 += bf_hi(vA.x); s2 += bf_lo(vA.y); s3 += bf_hi(vA.y);
        s4 += bf_lo(vA.z); s5 += bf_hi(vA.z); s6 += bf_lo(vA.w); s7 += bf_hi(vA.w);
        s0 += bf_lo(vB.x); s1 += bf_hi(vB.x); s2 += bf_lo(vB.y); s3 += bf_hi(vB.y);
        s4 += bf_lo(vB.z); s5 += bf_hi(vB.z); s6 += bf_lo(vB.w); s7 += bf_hi(vB.w);
        k += 8;
    }
    for (; k < end; k += 4) {
        unsigned int e = k + sub;
        if (e < end) {
            int sA = edge_src[e];
            uint4 vA = table[(long long)sA * 16 + c];
            s0 += bf_lo(vA.x); s1 += bf_hi(vA.x); s2 += bf_lo(vA.y); s3 += bf_hi(vA.y);
            s4 += bf_lo(vA.z); s5 += bf_hi(vA.z); s6 += bf_lo(vA.w); s7 += bf_hi(vA.w);
        }
    }
    s0 += __shfl_xor(s0, 16, 64); s1 += __shfl_xor(s1, 16, 64);
    s2 += __shfl_xor(s2, 16, 64); s3 += __shfl_xor(s3, 16, 64);
    s4 += __shfl_xor(s4, 16, 64); s5 += __shfl_xor(s5, 16, 64);
    s6 += __shfl_xor(s6, 16, 64); s7 += __shfl_xor(s7, 16, 64);
    s0 += __shfl_xor(s0, 32, 64); s1 += __shfl_xor(s1, 32, 64);
    s2 += __shfl_xor(s2, 32, 64); s3 += __shfl_xor(s3, 32, 64);
    s4 += __shfl_xor(s4, 32, 64); s5 += __shfl_xor(s5, 32, 64);
    s6 += __shfl_xor(s6, 32, 64); s7 += __shfl_xor(s7, 32, 64);
    if (sub == 0) {
        float inv = deg_inv[wave];
        float4 r0 = {s0 * inv, s1 * inv, s2 * inv, s3 * inv};
        float4 r1 = {s4 * inv, s5 * inv, s6 * inv, s7 * inv};
        float4* orow = (float4*)(h_out + (long long)wave * out_stride);
        nt_store4(r0, orow + c * 2);
        nt_store4(r1, orow + c * 2 + 1);
        if (bf_out) {
            ushort4 b0; b0.x = f2bf(r0.x); b0.y = f2bf(r0.y); b0.z = f2bf(r0.z); b0.w = f2bf(r0.w);
            ushort4 b1; b1.x = f2bf(r1.x); b1.y = f2bf(r1.y); b1.z = f2bf(r1.z); b1.w = f2bf(r1.w);
            bf_out[(long long)wave * 32 + c * 2]     = b0;
            bf_out[(long long)wave * 32 + c * 2 + 1] = b1;
        }
    }
}

// fp32 fallback gather (half-wave per edge, float4 per lane)
__global__ __launch_bounds__(256) void gather_mean_kernel(const unsigned int* __restrict__ offsets,
                                   const int* __restrict__ edge_src,
                                   const float* __restrict__ h_in, int in_stride,
                                   float* __restrict__ h_out, int out_stride,
                                   const float* __restrict__ deg_inv, int n) {
    int wave = (blockIdx.x * blockDim.x + threadIdx.x) >> 6;
    if (wave >= n) return;
    int lane = threadIdx.x & 63;
    int half = lane >> 5;
    int c = lane & 31;
    unsigned int beg = (wave > 0) ? offsets[wave - 1] : 0u;
    unsigned int end = offsets[wave];
    const float4* hp = (const float4*)h_in;
    int s4 = in_stride >> 2;

    float ax = 0.f, ay = 0.f, az = 0.f, aw = 0.f;
    unsigned int k = beg;
    for (; k + 4 <= end; k += 4) {
        int sA = edge_src[k + half];
        int sB = edge_src[k + 2 + half];
        float4 vA = hp[(long long)sA * s4 + c];
        float4 vB = hp[(long long)sB * s4 + c];
        ax += vA.x + vB.x; ay += vA.y + vB.y; az += vA.z + vB.z; aw += vA.w + vB.w;
    }
    if (k + 2 <= end) {
        int sA = edge_src[k + half];
        float4 vA = hp[(long long)sA * s4 + c];
        ax += vA.x; ay += vA.y; az += vA.z; aw += vA.w;
        k += 2;
    }
    if (k + half < end) {
        int sA = edge_src[k + half];
        float4 vA = hp[(long long)sA * s4 + c];
        ax += vA.x; ay += vA.y; az += vA.z; aw += vA.w;
    }
    ax += __shfl_xor(ax, 32, 64);
    ay += __shfl_xor(ay, 32, 64);
    az += __shfl_xor(az, 32, 64);
    aw += __shfl_xor(aw, 32, 64);
    if (half == 0) {
        float inv = deg_inv[wave];
        float4 r = {ax * inv, ay * inv, az * inv, aw * inv};
        ((float4*)(h_out + (long long)wave * out_stride))[c] = r;
    }
}

extern "C" void kernel_launch(void* const* d_in, const int* in_sizes, int n_in,
                              void* d_out, int out_size, void* d_ws, size_t ws_size,
                              hipStream_t stream) {
    const float* feature = (const float*)d_in[0];
    const int* edge_index = (const int*)d_in[1];
    const int E = in_sizes[1] / 2;         // 1,600,000
    const int* src = edge_index;           // edge_index[0, :]
    const int* dst = edge_index + E;       // edge_index[1, :]

    float* out = (float*)d_out;

    // ws: deg_inv | offsets | bcnt(+done) | bbase(+pad) | btail | edge_src | featbf | h1bf
    // binned[E] aliases h1bf (dead until gather layer 1)
    char* ws = (char*)d_ws;
    float*        deg_inv  = (float*)ws;         ws += (size_t)N_NODES * 4;
    unsigned int* offsets  = (unsigned int*)ws;  ws += (size_t)N_NODES * 4;
    unsigned int* bcnt     = (unsigned int*)ws;  ws += (NB + 8) * 4;   // NB counters + done
    unsigned int* bbase    = (unsigned int*)ws;  ws += (NB + 4) * 4;   // 257 used, padded to 16B
    unsigned int* btail    = (unsigned int*)ws;  ws += NB * 4;
    int*          edge_src = (int*)ws;           ws += (size_t)E * 4;
    char*         tail_ws  = ws;
    ushort4*      featbf   = (ushort4*)ws;       ws += (size_t)N_NODES * DFEAT * 2;
    ushort4*      h1bf     = (ushort4*)ws;       ws += (size_t)N_NODES * DFEAT * 2;
    size_t need_bf = (size_t)(ws - (char*)d_ws);
    bool use_bf16 = (ws_size >= need_bf);
    unsigned int* binned = use_bf16 ? (unsigned int*)h1bf : (unsigned int*)tail_ws;

    // zero bucket counters + done counter (race-free w.r.t. prep's hist blocks)
    hipMemsetAsync(bcnt, 0, (NB + 1) * sizeof(unsigned int), stream);

    // fused copy/cast + histogram + scan
    const int CB = (N_NODES * 32 + 255) / 256;     // 12500 copy blocks
    prep_kernel<<<CB + HISTBLK, 256, 0, stream>>>((const float4*)feature, out,
                                                  use_bf16 ? featbf : (ushort4*)nullptr,
                                                  dst, bcnt, bbase, btail,
                                                  N_NODES, E, CB);

    bin_kernel<<<BINBLK, BINW, 0, stream>>>(src, dst, btail, binned, E);
    bucket_csr_kernel<<<NB, 512, 0, stream>>>(bbase, binned, offsets, deg_inv, edge_src);

    long long threads = (long long)N_NODES * 64;
    int blocks = (int)((threads + 255) / 256);
    if (use_bf16) {
        // layer 1: featbf -> out[:,128:256] (+ h1bf; overwrites binned, which is dead now)
        gather_mean_bf16_kernel<<<blocks, 256, 0, stream>>>(offsets, edge_src,
                                                            (const uint4*)featbf,
                                                            out + DFEAT, OUTW,
                                                            h1bf, deg_inv, N_NODES);
        // layer 2: h1bf -> out[:,256:384]
        gather_mean_bf16_kernel<<<blocks, 256, 0, stream>>>(offsets, edge_src,
                                                            (const uint4*)h1bf,
                                                            out + 2 * DFEAT, OUTW,
                                                            (ushort4*)nullptr, deg_inv, N_NODES);
    } else {
        gather_mean_kernel<<<blocks, 256, 0, stream>>>(offsets, edge_src,
                                                       feature, DFEAT,
                                                       out + DFEAT, OUTW,
                                                       deg_inv, N_NODES);
        gather_mean_kernel<<<blocks, 256, 0, stream>>>(offsets, edge_src,
                                                       out + DFEAT, OUTW,
                                                       out + 2 * DFEAT, OUTW,
                                                       deg_inv, N_NODES);
    }
}

// Round 10
// 392.395 us; speedup vs baseline: 1.0736x; 1.0665x over previous
//
#include <hip/hip_runtime.h>

#define N_NODES   100000
#define DFEAT     128
#define OUTW      384     // 3 * 128
#define NB        256     // dst buckets
#define NPB       391     // nodes per bucket (256*391 = 100096 >= 100000)
#define BCAP      8192    // per-bucket LDS staging capacity (mean 6250, sigma ~79)
#define BINW      1024    // threads per bin block
#define BINBLK    256     // bin grid (R4-proven)
#define BUFCAP    64      // per-bucket LDS chunk buffer (entries, R4-proven)

typedef float nfloat4 __attribute__((ext_vector_type(4)));   // native vec for nontemporal builtins

__device__ inline float bf_lo(unsigned int u) {
    union { unsigned int i; float f; } v; v.i = u << 16; return v.f;
}
__device__ inline float bf_hi(unsigned int u) {
    union { unsigned int i; float f; } v; v.i = u & 0xFFFF0000u; return v.f;
}
__device__ inline unsigned short f2bf(float f) {
    union { float f; unsigned int i; } v; v.f = f;
    unsigned int r = (v.i + 0x7FFFu + ((v.i >> 16) & 1u)) >> 16;  // RNE
    return (unsigned short)r;
}
__device__ inline void nt_store4(float4 v, float4* p) {
    nfloat4 nv; nv.x = v.x; nv.y = v.y; nv.z = v.z; nv.w = v.w;
    __builtin_nontemporal_store(nv, (nfloat4*)p);
}

// out[row,0:128] = feature[row]; featbf[row] = bf16(feature[row])
__global__ void copy_cast_kernel(const float4* __restrict__ feat4, float* __restrict__ out,
                                 ushort4* __restrict__ featbf, int n) {
    int idx = blockIdx.x * blockDim.x + threadIdx.x;
    int row = idx >> 5;
    int c = idx & 31;
    if (row >= n) return;
    float4 v = feat4[(long long)row * 32 + c];
    // fp32 out columns are never re-read -> non-temporal
    nt_store4(v, (float4*)(out + (long long)row * OUTW) + c);
    ushort4 b; b.x = f2bf(v.x); b.y = f2bf(v.y); b.z = f2bf(v.z); b.w = f2bf(v.w);
    featbf[(long long)row * 32 + c] = b;
}

// fp32-fallback copy (no bf16 table)
__global__ void copy_feat_kernel(const float4* __restrict__ feat4, float* __restrict__ out, int n) {
    int idx = blockIdx.x * blockDim.x + threadIdx.x;
    int row = idx >> 5;
    int c = idx & 31;
    if (row >= n) return;
    ((float4*)(out + (long long)row * OUTW))[c] = feat4[(long long)row * 32 + c];
}

// ---------------- bucketed CSR build ----------------

// Pass 1: bucket histogram (LDS-staged, int4 loads).
__global__ __launch_bounds__(256) void hist_kernel(const int* __restrict__ dst,
                                                   unsigned int* __restrict__ bcnt, int E) {
    __shared__ unsigned int h[NB];
    int t = threadIdx.x;
    h[t] = 0u;
    __syncthreads();
    int E4 = E >> 2;
    const int4* d4 = (const int4*)dst;
    for (int i = blockIdx.x * blockDim.x + t; i < E4; i += gridDim.x * blockDim.x) {
        int4 v = d4[i];
        atomicAdd(&h[(unsigned int)v.x / NPB], 1u);
        atomicAdd(&h[(unsigned int)v.y / NPB], 1u);
        atomicAdd(&h[(unsigned int)v.z / NPB], 1u);
        atomicAdd(&h[(unsigned int)v.w / NPB], 1u);
    }
    for (int e = (E4 << 2) + blockIdx.x * blockDim.x + t; e < E; e += gridDim.x * blockDim.x)
        atomicAdd(&h[(unsigned int)dst[e] / NPB], 1u);
    __syncthreads();
    if (h[t]) atomicAdd(&bcnt[t], h[t]);
}

// Pass 2: exclusive scan of 256 bucket counts -> base[257], tail[256] (=base copy for bin pass)
__global__ __launch_bounds__(256) void bscan_kernel(const unsigned int* __restrict__ bcnt,
                                                    unsigned int* __restrict__ base,
                                                    unsigned int* __restrict__ tail) {
    __shared__ unsigned int s[NB];
    int t = threadIdx.x;
    s[t] = bcnt[t];
    __syncthreads();
    for (int d = 1; d < NB; d <<= 1) {
        unsigned int x = (t >= d) ? s[t - d] : 0u;
        __syncthreads();
        s[t] += x;
        __syncthreads();
    }
    unsigned int excl = (t > 0) ? s[t - 1] : 0u;
    base[t] = excl;
    tail[t] = excl;
    if (t == NB - 1) base[NB] = s[t];
}

// Pass 3: bin edges into bucket regions. 1024 threads, 4 edges/thread via int4.
// Per-bucket LDS chunks flushed as full 64B lines (tail atomics claim 16 slots at once).
// Rare overflow -> direct single write (correct for any distribution).
// entry = (src << 9) | (dst - bucket*NPB)   [src<2^17, dst_low<512]
__global__ __launch_bounds__(BINW) void bin_kernel(const int* __restrict__ src,
                                                   const int* __restrict__ dst,
                                                   unsigned int* __restrict__ tail,
                                                   unsigned int* __restrict__ binned, int E) {
    __shared__ unsigned int cnt[NB];
    __shared__ unsigned int buf[NB][BUFCAP];
    int t = threadIdx.x;
    if (t < NB) cnt[t] = 0u;
    __syncthreads();
    int chunk = ((E + (int)gridDim.x * 4 - 1) / ((int)gridDim.x * 4)) * 4;  // multiple of 4
    int s0 = blockIdx.x * chunk;
    int s1 = s0 + chunk; if (s1 > E) s1 = E;
    bool vec_ok = ((E & 3) == 0);   // dst = edge_index + E stays 16B-aligned

    for (int base_e = s0; base_e < s1; base_e += BINW * 4) {
        int e0 = base_e + t * 4;
        int4 d4, r4;
        int nvalid = 0;
        if (vec_ok && e0 + 3 < s1) {
            d4 = *(const int4*)(dst + e0);
            r4 = *(const int4*)(src + e0);
            nvalid = 4;
        } else {
            int tmp_d[4] = {0, 0, 0, 0}, tmp_s[4] = {0, 0, 0, 0};
            for (int j = 0; j < 4; ++j) {
                if (e0 + j < s1) { tmp_d[j] = dst[e0 + j]; tmp_s[j] = src[e0 + j]; nvalid = j + 1; }
            }
            d4 = make_int4(tmp_d[0], tmp_d[1], tmp_d[2], tmp_d[3]);
            r4 = make_int4(tmp_s[0], tmp_s[1], tmp_s[2], tmp_s[3]);
        }
        int dv[4] = {d4.x, d4.y, d4.z, d4.w};
        int sv[4] = {r4.x, r4.y, r4.z, r4.w};
        #pragma unroll
        for (int j = 0; j < 4; ++j) {
            if (j < nvalid) {
                unsigned int d = (unsigned int)dv[j];
                unsigned int b = d / NPB;
                unsigned int entry = ((unsigned int)sv[j] << 9) | (d - b * NPB);
                unsigned int pos = atomicAdd(&cnt[b], 1u);
                if (pos < BUFCAP) buf[b][pos] = entry;
                else { unsigned int g = atomicAdd(&tail[b], 1u); binned[g] = entry; }
            }
        }
        __syncthreads();
        if (t < NB) {
            unsigned int c = cnt[t]; if (c > BUFCAP) c = BUFCAP;
            unsigned int nch = c >> 4;
            if (nch) {
                unsigned int nfl = nch << 4;
                unsigned int g = atomicAdd(&tail[t], nfl);
                if ((g & 3u) == 0u) {
                    uint4* p = (uint4*)(binned + g);
                    for (unsigned int j = 0; j < nch * 4u; ++j)
                        p[j] = make_uint4(buf[t][4 * j], buf[t][4 * j + 1],
                                          buf[t][4 * j + 2], buf[t][4 * j + 3]);
                } else {
                    for (unsigned int j = 0; j < nfl; ++j) binned[g + j] = buf[t][j];
                }
                unsigned int rem = c - nfl;
                for (unsigned int j = 0; j < rem; ++j) buf[t][j] = buf[t][nfl + j];
                cnt[t] = rem;
            } else {
                cnt[t] = c;
            }
        }
        __syncthreads();
    }
    if (t < NB) {
        unsigned int c = cnt[t]; if (c > BUFCAP) c = BUFCAP;
        if (c) {
            unsigned int g = atomicAdd(&tail[t], c);
            for (unsigned int j = 0; j < c; ++j) binned[g + j] = buf[t][j];
        }
    }
}

// Pass 4: per-bucket exact counting sort in LDS; coalesced writeback of edge_src;
// writes offsets (inclusive end, same convention as gather) and deg_inv.
__global__ __launch_bounds__(512) void bucket_csr_kernel(const unsigned int* __restrict__ base,
                                                         const unsigned int* __restrict__ binned,
                                                         unsigned int* __restrict__ offsets,
                                                         float* __restrict__ deg_inv,
                                                         int* __restrict__ edge_src) {
    __shared__ unsigned int ncnt[NPB + 1];   // counters, reused as running placement offsets
    __shared__ unsigned int scanA[512];
    __shared__ unsigned int stage[BCAP];
    int b = blockIdx.x, t = threadIdx.x;     // t in 0..511
    unsigned int beg = base[b], end = base[b + 1];
    unsigned int n = end - beg;

    if (t < NPB) ncnt[t] = 0u;
    __syncthreads();
    for (unsigned int i = t; i < n; i += 512) {
        unsigned int e = binned[beg + i];
        atomicAdd(&ncnt[e & 511u], 1u);
    }
    __syncthreads();
    // Hillis-Steele inclusive scan over 512 padded elements (1 per thread)
    scanA[t] = (t < NPB) ? ncnt[t] : 0u;
    __syncthreads();
    for (int d = 1; d < 512; d <<= 1) {
        unsigned int x = (t >= d) ? scanA[t - d] : 0u;
        __syncthreads();
        scanA[t] += x;
        __syncthreads();
    }
    // node outputs + init run counters
    int gbase = b * NPB;
    if (t < NPB) {
        unsigned int incl = scanA[t];
        unsigned int excl = (t > 0) ? scanA[t - 1] : 0u;
        int g = gbase + t;
        if (g < N_NODES) {
            offsets[g] = beg + incl;
            unsigned int dg = incl - excl;
            deg_inv[g] = (dg > 0u) ? (1.0f / (float)dg) : 0.0f;
        }
        ncnt[t] = excl;   // running offset for placement
    }
    __syncthreads();
    if (n <= BCAP) {
        for (unsigned int i = t; i < n; i += 512) {
            unsigned int e = binned[beg + i];
            unsigned int pos = atomicAdd(&ncnt[e & 511u], 1u);
            stage[pos] = e >> 9;
        }
        __syncthreads();
        for (unsigned int i = t; i < n; i += 512)
            edge_src[beg + i] = (int)stage[i];
    } else {
        // fallback: correct for any degenerate bucket size (scattered global writes)
        for (unsigned int i = t; i < n; i += 512) {
            unsigned int e = binned[beg + i];
            unsigned int pos = atomicAdd(&ncnt[e & 511u], 1u);
            edge_src[beg + pos] = (int)(e >> 9);
        }
    }
}

// ---------------- gather ----------------

// bf16-table gather: one wave per node, quarter-wave (16 lanes) per edge.
// Main loop: 16 edges/iter -> 4 independent uint4 row loads in flight per lane.
__global__ __launch_bounds__(256) void gather_mean_bf16_kernel(
        const unsigned int* __restrict__ offsets,
        const int* __restrict__ edge_src,
        const uint4* __restrict__ table,        // bf16 rows, 16 uint4 per row
        float* __restrict__ h_out, int out_stride,
        ushort4* __restrict__ bf_out,           // may be null
        const float* __restrict__ deg_inv, int n) {
    int wv = (blockIdx.x * blockDim.x + threadIdx.x) >> 6;
    if (wv >= n) return;
    int wave = __builtin_amdgcn_readfirstlane(wv);   // wave-uniform -> scalar loads
    int lane = threadIdx.x & 63;
    int sub = lane >> 4;     // 0..3 : which edge of the group of 4
    int c = lane & 15;       // 16B chunk within row
    unsigned int beg = (wave > 0) ? offsets[wave - 1] : 0u;
    unsigned int end = offsets[wave];

    float s0 = 0.f, s1 = 0.f, s2 = 0.f, s3 = 0.f, s4 = 0.f, s5 = 0.f, s6 = 0.f, s7 = 0.f;
    unsigned int k = beg;
    for (; k + 16 <= end; k += 16) {
        int sA = edge_src[k + sub];
        int sB = edge_src[k + 4 + sub];
        int sC = edge_src[k + 8 + sub];
        int sD = edge_src[k + 12 + sub];
        uint4 vA = table[(long long)sA * 16 + c];
        uint4 vB = table[(long long)sB * 16 + c];
        uint4 vC = table[(long long)sC * 16 + c];
        uint4 vD = table[(long long)sD * 16 + c];
        s0 += bf_lo(vA.x); s1 += bf_hi(vA.x); s2 += bf_lo(vA.y); s3 += bf_hi(vA.y);
        s4 += bf_lo(vA.z); s5 += bf_hi(vA.z); s6 += bf_lo(vA.w); s7 += bf_hi(vA.w);
        s0 += bf_lo(vB.x); s1 += bf_hi(vB.x); s2 += bf_lo(vB.y); s3 += bf_hi(vB.y);
        s4 += bf_lo(vB.z); s5 += bf_hi(vB.z); s6 += bf_lo(vB.w); s7 += bf_hi(vB.w);
        s0 += bf_lo(vC.x); s1 += bf_hi(vC.x); s2 += bf_lo(vC.y); s3 += bf_hi(vC.y);
        s4 += bf_lo(vC.z); s5 += bf_hi(vC.z); s6 += bf_lo(vC.w); s7 += bf_hi(vC.w);
        s0 += bf_lo(vD.x); s1 += bf_hi(vD.x); s2 += bf_lo(vD.y); s3 += bf_hi(vD.y);
        s4 += bf_lo(vD.z); s5 += bf_hi(vD.z); s6 += bf_lo(vD.w); s7 += bf_hi(vD.w);
    }
    if (k + 8 <= end) {
        int sA = edge_src[k + sub];
        int sB = edge_src[k + 4 + sub];
        uint4 vA = table[(long long)sA * 16 + c];
        uint4 vB = table[(long long)sB * 16 + c];
        s0 += bf_lo(vA.x); s1 += bf_hi(vA.x); s2 += bf_lo(vA.y); s3 += bf_hi(vA.y);
        s4 += bf_lo(vA.z); s5 += bf_hi(vA.z); s6 += bf_lo(vA.w); s7 += bf_hi(vA.w);
        s0 += bf_lo(vB.x); s1 += bf_hi(vB.x); s2 += bf_lo(vB.y); s3 += bf_hi(vB.y);
        s4 += bf_lo(vB.z); s5 += bf_hi(vB.z); s6 += bf_lo(vB.w); s7 += bf_hi(vB.w);
        k += 8;
    }
    for (; k < end; k += 4) {
        unsigned int e = k + sub;
        if (e < end) {
            int sA = edge_src[e];
            uint4 vA = table[(long long)sA * 16 + c];
            s0 += bf_lo(vA.x); s1 += bf_hi(vA.x); s2 += bf_lo(vA.y); s3 += bf_hi(vA.y);
            s4 += bf_lo(vA.z); s5 += bf_hi(vA.z); s6 += bf_lo(vA.w); s7 += bf_hi(vA.w);
        }
    }
    s0 += __shfl_xor(s0, 16, 64); s1 += __shfl_xor(s1, 16, 64);
    s2 += __shfl_xor(s2, 16, 64); s3 += __shfl_xor(s3, 16, 64);
    s4 += __shfl_xor(s4, 16, 64); s5 += __shfl_xor(s5, 16, 64);
    s6 += __shfl_xor(s6, 16, 64); s7 += __shfl_xor(s7, 16, 64);
    s0 += __shfl_xor(s0, 32, 64); s1 += __shfl_xor(s1, 32, 64);
    s2 += __shfl_xor(s2, 32, 64); s3 += __shfl_xor(s3, 32, 64);
    s4 += __shfl_xor(s4, 32, 64); s5 += __shfl_xor(s5, 32, 64);
    s6 += __shfl_xor(s6, 32, 64); s7 += __shfl_xor(s7, 32, 64);
    if (sub == 0) {
        float inv = deg_inv[wave];
        float4 r0 = {s0 * inv, s1 * inv, s2 * inv, s3 * inv};
        float4 r1 = {s4 * inv, s5 * inv, s6 * inv, s7 * inv};
        float4* orow = (float4*)(h_out + (long long)wave * out_stride);
        nt_store4(r0, orow + c * 2);
        nt_store4(r1, orow + c * 2 + 1);
        if (bf_out) {
            ushort4 b0; b0.x = f2bf(r0.x); b0.y = f2bf(r0.y); b0.z = f2bf(r0.z); b0.w = f2bf(r0.w);
            ushort4 b1; b1.x = f2bf(r1.x); b1.y = f2bf(r1.y); b1.z = f2bf(r1.z); b1.w = f2bf(r1.w);
            bf_out[(long long)wave * 32 + c * 2]     = b0;
            bf_out[(long long)wave * 32 + c * 2 + 1] = b1;
        }
    }
}

// fp32 fallback gather (half-wave per edge, float4 per lane)
__global__ __launch_bounds__(256) void gather_mean_kernel(const unsigned int* __restrict__ offsets,
                                   const int* __restrict__ edge_src,
                                   const float* __restrict__ h_in, int in_stride,
                                   float* __restrict__ h_out, int out_stride,
                                   const float* __restrict__ deg_inv, int n) {
    int wave = (blockIdx.x * blockDim.x + threadIdx.x) >> 6;
    if (wave >= n) return;
    int lane = threadIdx.x & 63;
    int half = lane >> 5;
    int c = lane & 31;
    unsigned int beg = (wave > 0) ? offsets[wave - 1] : 0u;
    unsigned int end = offsets[wave];
    const float4* hp = (const float4*)h_in;
    int s4 = in_stride >> 2;

    float ax = 0.f, ay = 0.f, az = 0.f, aw = 0.f;
    unsigned int k = beg;
    for (; k + 4 <= end; k += 4) {
        int sA = edge_src[k + half];
        int sB = edge_src[k + 2 + half];
        float4 vA = hp[(long long)sA * s4 + c];
        float4 vB = hp[(long long)sB * s4 + c];
        ax += vA.x + vB.x; ay += vA.y + vB.y; az += vA.z + vB.z; aw += vA.w + vB.w;
    }
    if (k + 2 <= end) {
        int sA = edge_src[k + half];
        float4 vA = hp[(long long)sA * s4 + c];
        ax += vA.x; ay += vA.y; az += vA.z; aw += vA.w;
        k += 2;
    }
    if (k + half < end) {
        int sA = edge_src[k + half];
        float4 vA = hp[(long long)sA * s4 + c];
        ax += vA.x; ay += vA.y; az += vA.z; aw += vA.w;
    }
    ax += __shfl_xor(ax, 32, 64);
    ay += __shfl_xor(ay, 32, 64);
    az += __shfl_xor(az, 32, 64);
    aw += __shfl_xor(aw, 32, 64);
    if (half == 0) {
        float inv = deg_inv[wave];
        float4 r = {ax * inv, ay * inv, az * inv, aw * inv};
        ((float4*)(h_out + (long long)wave * out_stride))[c] = r;
    }
}

extern "C" void kernel_launch(void* const* d_in, const int* in_sizes, int n_in,
                              void* d_out, int out_size, void* d_ws, size_t ws_size,
                              hipStream_t stream) {
    const float* feature = (const float*)d_in[0];
    const int* edge_index = (const int*)d_in[1];
    const int E = in_sizes[1] / 2;         // 1,600,000
    const int* src = edge_index;           // edge_index[0, :]
    const int* dst = edge_index + E;       // edge_index[1, :]

    float* out = (float*)d_out;

    // ws: deg_inv | offsets | bcnt | bbase(+pad) | btail | edge_src | featbf | h1bf
    // binned[E] aliases h1bf (dead until gather layer 1)
    char* ws = (char*)d_ws;
    float*        deg_inv  = (float*)ws;         ws += (size_t)N_NODES * 4;
    unsigned int* offsets  = (unsigned int*)ws;  ws += (size_t)N_NODES * 4;
    unsigned int* bcnt     = (unsigned int*)ws;  ws += NB * 4;
    unsigned int* bbase    = (unsigned int*)ws;  ws += (NB + 4) * 4;   // 257 used, padded to 16B
    unsigned int* btail    = (unsigned int*)ws;  ws += NB * 4;
    int*          edge_src = (int*)ws;           ws += (size_t)E * 4;
    char*         tail_ws  = ws;
    ushort4*      featbf   = (ushort4*)ws;       ws += (size_t)N_NODES * DFEAT * 2;
    ushort4*      h1bf     = (ushort4*)ws;       ws += (size_t)N_NODES * DFEAT * 2;
    size_t need_bf = (size_t)(ws - (char*)d_ws);
    bool use_bf16 = (ws_size >= need_bf);
    unsigned int* binned = use_bf16 ? (unsigned int*)h1bf : (unsigned int*)tail_ws;

    hipMemsetAsync(bcnt, 0, NB * sizeof(unsigned int), stream);

    // out[:,0:128] = feature (+ bf16 cast)
    {
        int nthreads = N_NODES * 32;
        if (use_bf16)
            copy_cast_kernel<<<(nthreads + 255) / 256, 256, 0, stream>>>((const float4*)feature, out, featbf, N_NODES);
        else
            copy_feat_kernel<<<(nthreads + 255) / 256, 256, 0, stream>>>((const float4*)feature, out, N_NODES);
    }

    // bucketed CSR build
    hist_kernel<<<256, 256, 0, stream>>>(dst, bcnt, E);
    bscan_kernel<<<1, 256, 0, stream>>>(bcnt, bbase, btail);
    bin_kernel<<<BINBLK, BINW, 0, stream>>>(src, dst, btail, binned, E);
    bucket_csr_kernel<<<NB, 512, 0, stream>>>(bbase, binned, offsets, deg_inv, edge_src);

    long long threads = (long long)N_NODES * 64;
    int blocks = (int)((threads + 255) / 256);
    if (use_bf16) {
        // layer 1: featbf -> out[:,128:256] (+ h1bf; overwrites binned, which is dead now)
        gather_mean_bf16_kernel<<<blocks, 256, 0, stream>>>(offsets, edge_src,
                                                            (const uint4*)featbf,
                                                            out + DFEAT, OUTW,
                                                            h1bf, deg_inv, N_NODES);
        // layer 2: h1bf -> out[:,256:384]
        gather_mean_bf16_kernel<<<blocks, 256, 0, stream>>>(offsets, edge_src,
                                                            (const uint4*)h1bf,
                                                            out + 2 * DFEAT, OUTW,
                                                            (ushort4*)nullptr, deg_inv, N_NODES);
    } else {
        gather_mean_kernel<<<blocks, 256, 0, stream>>>(offsets, edge_src,
                                                       feature, DFEAT,
                                                       out + DFEAT, OUTW,
                                                       deg_inv, N_NODES);
        gather_mean_kernel<<<blocks, 256, 0, stream>>>(offsets, edge_src,
                                                       out + DFEAT, OUTW,
                                                       out + 2 * DFEAT, OUTW,
                                                       deg_inv, N_NODES);
    }
}